// Round 1
// baseline (430.364 us; speedup 1.0000x reference)
//
#include <hip/hip_runtime.h>

#define R_ 256
#define B_ 64
#define D_ 512
#define N_ 16
#define K_ 4
#define RBD (B_ * D_)          // 32768 floats per region
#define OUT_ELEMS (R_ * B_ * D_)

// ---------------------------------------------------------------------------
// Kernel 1: sims (un-normalized dot products; /(B*D) is monotone -> skipped)
// + stable top-4 selection (strict >, first index wins = jax.lax.top_k ties)
// One block per region; each of 4 waves owns 4 neighbor positions.
// ---------------------------------------------------------------------------
__global__ __launch_bounds__(256) void sims_topk_kernel(
    const float* __restrict__ h, const int* __restrict__ nbrs,
    int* __restrict__ sel, float* __restrict__ fanin) {
  const int r = blockIdx.x;
  const int t = threadIdx.x;
  const int lane = t & 63;
  const int wave = t >> 6;
  __shared__ float sims_s[N_];
  __shared__ int nb_s[N_];
  if (t < N_) nb_s[t] = nbrs[r * N_ + t];
  __syncthreads();
  const int n0 = wave * 4;
  const float4* hr  = (const float4*)(h + (size_t)r * RBD);
  const float4* hn0 = (const float4*)(h + (size_t)nb_s[n0 + 0] * RBD);
  const float4* hn1 = (const float4*)(h + (size_t)nb_s[n0 + 1] * RBD);
  const float4* hn2 = (const float4*)(h + (size_t)nb_s[n0 + 2] * RBD);
  const float4* hn3 = (const float4*)(h + (size_t)nb_s[n0 + 3] * RBD);
  float a0 = 0.f, a1 = 0.f, a2 = 0.f, a3 = 0.f;
  for (int i = lane; i < RBD / 4; i += 64) {
    float4 x = hr[i];
    float4 y0 = hn0[i], y1 = hn1[i], y2 = hn2[i], y3 = hn3[i];
    a0 += x.x * y0.x + x.y * y0.y + x.z * y0.z + x.w * y0.w;
    a1 += x.x * y1.x + x.y * y1.y + x.z * y1.z + x.w * y1.w;
    a2 += x.x * y2.x + x.y * y2.y + x.z * y2.z + x.w * y2.w;
    a3 += x.x * y3.x + x.y * y3.y + x.z * y3.z + x.w * y3.w;
  }
  float v[4] = {a0, a1, a2, a3};
#pragma unroll
  for (int n = 0; n < 4; n++) {
    float x = v[n];
#pragma unroll
    for (int off = 32; off > 0; off >>= 1) x += __shfl_down(x, off);
    if (lane == 0) sims_s[n0 + n] = x;
  }
  __syncthreads();
  if (t == 0) {
    unsigned used = 0;
#pragma unroll
    for (int k = 0; k < K_; k++) {
      float best = -3.0e38f;
      int bi = 0;
      for (int n = 0; n < N_; n++) {
        if (used & (1u << n)) continue;
        float vv = sims_s[n];
        if (vv > best) { best = vv; bi = n; }
      }
      used |= 1u << bi;
      sel[r * K_ + k] = nb_s[bi];
    }
    if (r == 0) *fanin = 4.0f;
  }
}

// ---------------------------------------------------------------------------
// Kernel 2: W2eff[e][d] = sum_c W_merge[e][512+c] * W_msg[c][d]   (512x512x512)
// ---------------------------------------------------------------------------
__global__ __launch_bounds__(256) void w2eff_kernel(
    const float* __restrict__ Wm, const float* __restrict__ Wmsg,
    float* __restrict__ W2) {
  __shared__ float As[32][33];
  __shared__ float Bs[32][33];
  const int t = threadIdx.x;
  const int eb = blockIdx.y * 32;
  const int db = blockIdx.x * 32;
  const int tx = t % 16, ty = t / 16;
  const int lr = t / 8;          // 0..31
  const int lc = (t % 8) * 4;    // 0,4,...,28
  float a00 = 0.f, a01 = 0.f, a10 = 0.f, a11 = 0.f;
  for (int c0 = 0; c0 < 512; c0 += 32) {
    float4 av = *(const float4*)&Wm[(size_t)(eb + lr) * 1024 + 512 + c0 + lc];
    float4 bv = *(const float4*)&Wmsg[(size_t)(c0 + lr) * 512 + db + lc];
    As[lr][lc + 0] = av.x; As[lr][lc + 1] = av.y;
    As[lr][lc + 2] = av.z; As[lr][lc + 3] = av.w;
    Bs[lr][lc + 0] = bv.x; Bs[lr][lc + 1] = bv.y;
    Bs[lr][lc + 2] = bv.z; Bs[lr][lc + 3] = bv.w;
    __syncthreads();
#pragma unroll
    for (int kk = 0; kk < 32; kk++) {
      float x0 = As[2 * ty + 0][kk], x1 = As[2 * ty + 1][kk];
      float y0 = Bs[kk][2 * tx + 0], y1 = Bs[kk][2 * tx + 1];
      a00 += x0 * y0; a01 += x0 * y1;
      a10 += x1 * y0; a11 += x1 * y1;
    }
    __syncthreads();
  }
  W2[(size_t)(eb + 2 * ty + 0) * 512 + db + 2 * tx + 0] = a00;
  W2[(size_t)(eb + 2 * ty + 0) * 512 + db + 2 * tx + 1] = a01;
  W2[(size_t)(eb + 2 * ty + 1) * 512 + db + 2 * tx + 0] = a10;
  W2[(size_t)(eb + 2 * ty + 1) * 512 + db + 2 * tx + 1] = a11;
}

// ---------------------------------------------------------------------------
// Kernel 3: bias_eff[e] = b_merge[e] + sum_c b_msg[c] * W_merge[e][512+c]
// ---------------------------------------------------------------------------
__global__ __launch_bounds__(256) void bias_kernel(
    const float* __restrict__ Wm, const float* __restrict__ b_msg,
    const float* __restrict__ b_merge, float* __restrict__ bias_eff) {
  const int e = blockIdx.x * 256 + threadIdx.x;  // 0..511
  const float4* bp = (const float4*)b_msg;
  const float4* wp = (const float4*)&Wm[(size_t)e * 1024 + 512];
  float acc = 0.f;
  for (int c = 0; c < 128; c++) {
    float4 b4 = bp[c], w4 = wp[c];
    acc += b4.x * w4.x + b4.y * w4.y + b4.z * w4.z + b4.w * w4.w;
  }
  bias_eff[e] = acc + b_merge[e];
}

// ---------------------------------------------------------------------------
// Kernel 4: fused gather + GEMM.
// out[r][b][e] = bias_eff[e] + sum_{d<512} h[r][b][d]*Wm[e][d]
//                           + sum_{d<512} hbar[r][b][d]*W2eff[e][d]
// hbar gathered on the fly from sel. Tile: BM=64 (all b), BN=256, BK=32.
// 256 threads, 8x8 register tile per thread. LDS ~42 KB -> 3 blocks/CU.
// ---------------------------------------------------------------------------
#define BM 64
#define BN 256
#define BK 32

__global__ __launch_bounds__(256) void fused_gemm_kernel(
    const float* __restrict__ h, const int* __restrict__ sel,
    const float* __restrict__ Wm, const float* __restrict__ W2,
    const float* __restrict__ bias_eff, float* __restrict__ out) {
  const int r = blockIdx.y;
  const int eb = blockIdx.x * BN;
  const int t = threadIdx.x;
  __shared__ float As[BM][BK + 1];
  __shared__ float Ws[BN][BK + 1];
  __shared__ int sel_s[K_];
  if (t < K_) sel_s[t] = sel[r * K_ + t];
  __syncthreads();
  const size_t hr = (size_t)r * RBD;
  const size_t s0 = (size_t)sel_s[0] * RBD;
  const size_t s1 = (size_t)sel_s[1] * RBD;
  const size_t s2 = (size_t)sel_s[2] * RBD;
  const size_t s3 = (size_t)sel_s[3] * RBD;

  const int tb = t % 8;    // b sub-index
  const int te = t / 8;    // e sub-index 0..31
  const int ab = t / 4;    // staging: A row 0..63
  const int ac = (t % 4) * 8;  // staging: A col group

  float acc[8][8] = {};

  for (int d0 = 0; d0 < 1024; d0 += BK) {
    // ---- stage A tile ----
    if (d0 < 512) {
      const float* src = h + hr + (size_t)ab * 512 + d0 + ac;
      float4 v0 = *(const float4*)(src);
      float4 v1 = *(const float4*)(src + 4);
      As[ab][ac + 0] = v0.x; As[ab][ac + 1] = v0.y;
      As[ab][ac + 2] = v0.z; As[ab][ac + 3] = v0.w;
      As[ab][ac + 4] = v1.x; As[ab][ac + 5] = v1.y;
      As[ab][ac + 6] = v1.z; As[ab][ac + 7] = v1.w;
    } else {
      const size_t off = (size_t)ab * 512 + (d0 - 512) + ac;
      const float* p0 = h + s0 + off;
      const float* p1 = h + s1 + off;
      const float* p2 = h + s2 + off;
      const float* p3 = h + s3 + off;
      float4 q0 = *(const float4*)p0, q0b = *(const float4*)(p0 + 4);
      float4 q1 = *(const float4*)p1, q1b = *(const float4*)(p1 + 4);
      float4 q2 = *(const float4*)p2, q2b = *(const float4*)(p2 + 4);
      float4 q3 = *(const float4*)p3, q3b = *(const float4*)(p3 + 4);
      As[ab][ac + 0] = 0.25f * (q0.x + q1.x + q2.x + q3.x);
      As[ab][ac + 1] = 0.25f * (q0.y + q1.y + q2.y + q3.y);
      As[ab][ac + 2] = 0.25f * (q0.z + q1.z + q2.z + q3.z);
      As[ab][ac + 3] = 0.25f * (q0.w + q1.w + q2.w + q3.w);
      As[ab][ac + 4] = 0.25f * (q0b.x + q1b.x + q2b.x + q3b.x);
      As[ab][ac + 5] = 0.25f * (q0b.y + q1b.y + q2b.y + q3b.y);
      As[ab][ac + 6] = 0.25f * (q0b.z + q1b.z + q2b.z + q3b.z);
      As[ab][ac + 7] = 0.25f * (q0b.w + q1b.w + q2b.w + q3b.w);
    }
    // ---- stage W tile: row e_l = t (full 32-float row per thread) ----
    {
      const float* src = (d0 < 512)
          ? (Wm + (size_t)(eb + t) * 1024 + d0)
          : (W2 + (size_t)(eb + t) * 512 + (d0 - 512));
#pragma unroll
      for (int j = 0; j < 8; j++) {
        float4 v = *(const float4*)(src + 4 * j);
        Ws[t][4 * j + 0] = v.x; Ws[t][4 * j + 1] = v.y;
        Ws[t][4 * j + 2] = v.z; Ws[t][4 * j + 3] = v.w;
      }
    }
    __syncthreads();
    // ---- compute ----
#pragma unroll
    for (int kk = 0; kk < BK; kk++) {
      float a[8], w[8];
#pragma unroll
      for (int i = 0; i < 8; i++) a[i] = As[tb + 8 * i][kk];
#pragma unroll
      for (int j = 0; j < 8; j++) w[j] = Ws[te + 32 * j][kk];
#pragma unroll
      for (int i = 0; i < 8; i++)
#pragma unroll
        for (int j = 0; j < 8; j++) acc[i][j] += a[i] * w[j];
    }
    __syncthreads();
  }

  // ---- epilogue ----
  float be[8];
#pragma unroll
  for (int j = 0; j < 8; j++) be[j] = bias_eff[eb + te + 32 * j];
#pragma unroll
  for (int i = 0; i < 8; i++) {
    const int b = tb + 8 * i;
#pragma unroll
    for (int j = 0; j < 8; j++) {
      const int e = eb + te + 32 * j;
      out[hr + (size_t)b * 512 + e] = acc[i][j] + be[j];
    }
  }
}

// ---------------------------------------------------------------------------
extern "C" void kernel_launch(void* const* d_in, const int* in_sizes, int n_in,
                              void* d_out, int out_size, void* d_ws,
                              size_t ws_size, hipStream_t stream) {
  const float* h       = (const float*)d_in[0];
  const int*   nbrs    = (const int*)d_in[1];
  const float* W_msg   = (const float*)d_in[2];
  const float* b_msg   = (const float*)d_in[3];
  const float* W_merge = (const float*)d_in[4];
  const float* b_merge = (const float*)d_in[5];
  float* out = (float*)d_out;

  char* ws = (char*)d_ws;
  int*   sel      = (int*)ws;                              // 4 KB
  float* W2       = (float*)(ws + 4096);                   // 1 MB
  float* bias_eff = (float*)(ws + 4096 + 512 * 512 * 4);   // 2 KB

  sims_topk_kernel<<<R_, 256, 0, stream>>>(h, nbrs, sel, out + OUT_ELEMS);
  bias_kernel<<<2, 256, 0, stream>>>(W_merge, b_msg, b_merge, bias_eff);
  w2eff_kernel<<<dim3(16, 16), 256, 0, stream>>>(W_merge, W_msg, W2);
  fused_gemm_kernel<<<dim3(BN == 256 ? 2 : 4, R_), 256, 0, stream>>>(
      h, sel, W_merge, W2, bias_eff, out);
}

// Round 2
// 145.030 us; speedup vs baseline: 2.9674x; 2.9674x over previous
//
#include <hip/hip_runtime.h>
#include <hip/hip_bf16.h>

#define R_ 256
#define B_ 64
#define D_ 512
#define N_ 16
#define K_ 4
#define RBD (B_ * D_)          // 32768 floats per region
#define OUT_ELEMS (R_ * B_ * D_)
#define M_TOT (R_ * B_)        // 16384
#define K_TOT 1024

typedef __attribute__((address_space(1))) unsigned int g_u32;
typedef __attribute__((address_space(3))) unsigned int l_u32;
using f32x4 = __attribute__((ext_vector_type(4))) float;
using bf16x8 = __attribute__((ext_vector_type(8))) short;

__device__ inline unsigned short f2bf(float x) {
  __hip_bfloat16 b = __float2bfloat16(x);
  return *reinterpret_cast<unsigned short*>(&b);
}

// ---------------------------------------------------------------------------
// Kernel 1: fp32 sims + stable top-4 (ties -> lowest position, = lax.top_k)
// ---------------------------------------------------------------------------
__global__ __launch_bounds__(256) void sims_topk_kernel(
    const float* __restrict__ h, const int* __restrict__ nbrs,
    int* __restrict__ sel, float* __restrict__ fanin) {
  const int r = blockIdx.x;
  const int t = threadIdx.x;
  const int lane = t & 63;
  const int wave = t >> 6;
  __shared__ float sims_s[N_];
  __shared__ int nb_s[N_];
  if (t < N_) nb_s[t] = nbrs[r * N_ + t];
  __syncthreads();
  const int n0 = wave * 4;
  const float4* hr  = (const float4*)(h + (size_t)r * RBD);
  const float4* hn0 = (const float4*)(h + (size_t)nb_s[n0 + 0] * RBD);
  const float4* hn1 = (const float4*)(h + (size_t)nb_s[n0 + 1] * RBD);
  const float4* hn2 = (const float4*)(h + (size_t)nb_s[n0 + 2] * RBD);
  const float4* hn3 = (const float4*)(h + (size_t)nb_s[n0 + 3] * RBD);
  float a0 = 0.f, a1 = 0.f, a2 = 0.f, a3 = 0.f;
  for (int i = lane; i < RBD / 4; i += 64) {
    float4 x = hr[i];
    float4 y0 = hn0[i], y1 = hn1[i], y2 = hn2[i], y3 = hn3[i];
    a0 += x.x * y0.x + x.y * y0.y + x.z * y0.z + x.w * y0.w;
    a1 += x.x * y1.x + x.y * y1.y + x.z * y1.z + x.w * y1.w;
    a2 += x.x * y2.x + x.y * y2.y + x.z * y2.z + x.w * y2.w;
    a3 += x.x * y3.x + x.y * y3.y + x.z * y3.z + x.w * y3.w;
  }
  float v[4] = {a0, a1, a2, a3};
#pragma unroll
  for (int n = 0; n < 4; n++) {
    float x = v[n];
#pragma unroll
    for (int off = 32; off > 0; off >>= 1) x += __shfl_down(x, off);
    if (lane == 0) sims_s[n0 + n] = x;
  }
  __syncthreads();
  if (t == 0) {
    unsigned used = 0;
#pragma unroll
    for (int k = 0; k < K_; k++) {
      float best = -3.0e38f;
      int bi = 0;
      for (int n = 0; n < N_; n++) {
        if (used & (1u << n)) continue;
        float vv = sims_s[n];
        if (vv > best) { best = vv; bi = n; }
      }
      used |= 1u << bi;
      sel[r * K_ + k] = nb_s[bi];
    }
    if (r == 0) *fanin = 4.0f;
  }
}

// ---------------------------------------------------------------------------
// Kernel 2: W2eff[e][d] = sum_c Wm[e][512+c] * Wmsg[c][d], stored bf16 into
// Wbig[e][512+d]. (fp32 accumulate, bf16 store)
// ---------------------------------------------------------------------------
__global__ __launch_bounds__(256) void w2eff_kernel(
    const float* __restrict__ Wm, const float* __restrict__ Wmsg,
    unsigned short* __restrict__ Wbig) {
  __shared__ float As[32][33];
  __shared__ float Bs[32][33];
  const int t = threadIdx.x;
  const int eb = blockIdx.y * 32;
  const int db = blockIdx.x * 32;
  const int tx = t % 16, ty = t / 16;
  const int lr = t / 8;
  const int lc = (t % 8) * 4;
  float a00 = 0.f, a01 = 0.f, a10 = 0.f, a11 = 0.f;
  for (int c0 = 0; c0 < 512; c0 += 32) {
    float4 av = *(const float4*)&Wm[(size_t)(eb + lr) * 1024 + 512 + c0 + lc];
    float4 bv = *(const float4*)&Wmsg[(size_t)(c0 + lr) * 512 + db + lc];
    As[lr][lc + 0] = av.x; As[lr][lc + 1] = av.y;
    As[lr][lc + 2] = av.z; As[lr][lc + 3] = av.w;
    Bs[lr][lc + 0] = bv.x; Bs[lr][lc + 1] = bv.y;
    Bs[lr][lc + 2] = bv.z; Bs[lr][lc + 3] = bv.w;
    __syncthreads();
#pragma unroll
    for (int kk = 0; kk < 32; kk++) {
      float x0 = As[2 * ty + 0][kk], x1 = As[2 * ty + 1][kk];
      float y0 = Bs[kk][2 * tx + 0], y1 = Bs[kk][2 * tx + 1];
      a00 += x0 * y0; a01 += x0 * y1;
      a10 += x1 * y0; a11 += x1 * y1;
    }
    __syncthreads();
  }
  Wbig[(size_t)(eb + 2 * ty + 0) * 1024 + 512 + db + 2 * tx + 0] = f2bf(a00);
  Wbig[(size_t)(eb + 2 * ty + 0) * 1024 + 512 + db + 2 * tx + 1] = f2bf(a01);
  Wbig[(size_t)(eb + 2 * ty + 1) * 1024 + 512 + db + 2 * tx + 0] = f2bf(a10);
  Wbig[(size_t)(eb + 2 * ty + 1) * 1024 + 512 + db + 2 * tx + 1] = f2bf(a11);
}

// ---------------------------------------------------------------------------
// Kernel 3: bias_eff[e] = b_merge[e] + sum_c b_msg[c] * Wm[e][512+c]  (fp32)
// ---------------------------------------------------------------------------
__global__ __launch_bounds__(256) void bias_kernel(
    const float* __restrict__ Wm, const float* __restrict__ b_msg,
    const float* __restrict__ b_merge, float* __restrict__ bias_eff) {
  const int e = blockIdx.x * 256 + threadIdx.x;
  const float4* bp = (const float4*)b_msg;
  const float4* wp = (const float4*)&Wm[(size_t)e * 1024 + 512];
  float acc = 0.f;
  for (int c = 0; c < 128; c++) {
    float4 b4 = bp[c], w4 = wp[c];
    acc += b4.x * w4.x + b4.y * w4.y + b4.z * w4.z + b4.w * w4.w;
  }
  bias_eff[e] = acc + b_merge[e];
}

// ---------------------------------------------------------------------------
// Kernel 4: Wbig first half: Wbig[e][d] = bf16(Wm[e][d]) for d<512
// ---------------------------------------------------------------------------
__global__ __launch_bounds__(256) void wconv_kernel(
    const float* __restrict__ Wm, unsigned short* __restrict__ Wbig) {
  const int i = blockIdx.x * 256 + threadIdx.x;  // 0..65535 (float4 units)
  const int e = i >> 7;
  const int c4 = (i & 127) * 4;
  float4 v = *(const float4*)&Wm[(size_t)e * 1024 + c4];
  ushort4 o;
  o.x = f2bf(v.x); o.y = f2bf(v.y); o.z = f2bf(v.z); o.w = f2bf(v.w);
  *(ushort4*)&Wbig[(size_t)e * 1024 + c4] = o;
}

// ---------------------------------------------------------------------------
// Kernel 5: Abig[r*64+b][0..511] = bf16(h[r][b][:]);
//           Abig[r*64+b][512..1023] = bf16(mean_k h[sel[r][k]][b][:])
// ---------------------------------------------------------------------------
__global__ __launch_bounds__(256) void abig_kernel(
    const float* __restrict__ h, const int* __restrict__ sel,
    unsigned short* __restrict__ Abig) {
  const int r = blockIdx.x;
  const int t = threadIdx.x;
  __shared__ int sel_s[K_];
  if (t < K_) sel_s[t] = sel[r * K_ + t];
  __syncthreads();
  const size_t hr = (size_t)r * RBD;
  const size_t s0 = (size_t)sel_s[0] * RBD;
  const size_t s1 = (size_t)sel_s[1] * RBD;
  const size_t s2 = (size_t)sel_s[2] * RBD;
  const size_t s3 = (size_t)sel_s[3] * RBD;
  // 64 rows x 512 cols, float4 granularity: 8192 chunks
  for (int i = t; i < 8192; i += 256) {
    const int row = i >> 7;
    const int c = (i & 127) * 4;
    const size_t off = (size_t)row * 512 + c;
    float4 v = *(const float4*)&h[hr + off];
    ushort4 o;
    o.x = f2bf(v.x); o.y = f2bf(v.y); o.z = f2bf(v.z); o.w = f2bf(v.w);
    *(ushort4*)&Abig[((size_t)r * 64 + row) * 1024 + c] = o;
    float4 q0 = *(const float4*)&h[s0 + off];
    float4 q1 = *(const float4*)&h[s1 + off];
    float4 q2 = *(const float4*)&h[s2 + off];
    float4 q3 = *(const float4*)&h[s3 + off];
    ushort4 m;
    m.x = f2bf(0.25f * (q0.x + q1.x + q2.x + q3.x));
    m.y = f2bf(0.25f * (q0.y + q1.y + q2.y + q3.y));
    m.z = f2bf(0.25f * (q0.z + q1.z + q2.z + q3.z));
    m.w = f2bf(0.25f * (q0.w + q1.w + q2.w + q3.w));
    *(ushort4*)&Abig[((size_t)r * 64 + row) * 1024 + 512 + c] = m;
  }
}

// ---------------------------------------------------------------------------
// Kernel 6: bf16 MFMA GEMM. out[m][e] = bias[e] + sum_k Abig[m][k]*Wbig[e][k]
// M=16384, N=512, K=1024. Tile 128x128, BK=64 (128B rows in LDS).
// XOR-swizzled LDS (slot ^= row&7) via pre-swizzled global source (m173
// pattern: global_load_lds dest is linear, swizzle lives in src address).
// 4 waves as 2x2, each computes 64x64 via 4x4 frags of 16x16x32 MFMA.
// ---------------------------------------------------------------------------
__global__ __launch_bounds__(256) void mfma_gemm_kernel(
    const unsigned short* __restrict__ A, const unsigned short* __restrict__ W,
    const float* __restrict__ bias, float* __restrict__ out) {
  const int t = threadIdx.x;
  const int lane = t & 63;
  const int w = t >> 6;
  const int m0 = blockIdx.y * 128;
  const int eb = blockIdx.x * 128;
  __shared__ unsigned short As[128 * 64];  // 16 KB, rows of 128B, swizzled
  __shared__ unsigned short Ws[128 * 64];  // 16 KB
  const int wm = w >> 1, wn = w & 1;
  const int rlane = lane & 15;
  const int kq = lane >> 4;  // 0..3

  f32x4 acc[4][4] = {};

  const char* Ab = (const char*)A;
  const char* Wb = (const char*)W;
  char* smemA = (char*)As;
  char* smemW = (char*)Ws;
  const int row_in_sweep = t >> 3;  // 0..31
  const int slot_st = t & 7;

  for (int kt = 0; kt < 16; ++kt) {
    // ---- stage A and W tiles (global -> LDS direct, 16B/lane) ----
#pragma unroll
    for (int q = 0; q < 4; ++q) {
      const int row = q * 32 + row_in_sweep;
      const int slot = slot_st ^ (row & 7);
      const char* ga = Ab + ((size_t)(m0 + row) * 2048 + kt * 128 + slot * 16);
      const char* gw = Wb + ((size_t)(eb + row) * 2048 + kt * 128 + slot * 16);
      char* la = smemA + q * 4096 + w * 1024;  // wave-uniform; HW adds lane*16
      char* lw = smemW + q * 4096 + w * 1024;
      __builtin_amdgcn_global_load_lds((const g_u32*)ga, (l_u32*)la, 16, 0, 0);
      __builtin_amdgcn_global_load_lds((const g_u32*)gw, (l_u32*)lw, 16, 0, 0);
    }
    __syncthreads();  // compiler drains vmcnt before s_barrier
    // ---- compute: 2 k-steps of 32 ----
#pragma unroll
    for (int ks = 0; ks < 2; ++ks) {
      bf16x8 a[4], b[4];
#pragma unroll
      for (int i = 0; i < 4; ++i) {
        const int row = wm * 64 + i * 16 + rlane;
        const int slot = (ks * 4 + kq) ^ (row & 7);
        a[i] = *(const bf16x8*)(smemA + row * 128 + slot * 16);
      }
#pragma unroll
      for (int j = 0; j < 4; ++j) {
        const int row = wn * 64 + j * 16 + rlane;
        const int slot = (ks * 4 + kq) ^ (row & 7);
        b[j] = *(const bf16x8*)(smemW + row * 128 + slot * 16);
      }
#pragma unroll
      for (int i = 0; i < 4; ++i)
#pragma unroll
        for (int j = 0; j < 4; ++j)
          acc[i][j] = __builtin_amdgcn_mfma_f32_16x16x32_bf16(
              a[i], b[j], acc[i][j], 0, 0, 0);
    }
    __syncthreads();  // all reads done before next stage overwrites
  }

  // ---- epilogue: D row = kq*4+reg, col = rlane (m89-verified layout) ----
  float bj[4];
#pragma unroll
  for (int j = 0; j < 4; ++j) bj[j] = bias[eb + wn * 64 + j * 16 + rlane];
#pragma unroll
  for (int i = 0; i < 4; ++i) {
#pragma unroll
    for (int reg = 0; reg < 4; ++reg) {
      const size_t m = (size_t)m0 + wm * 64 + i * 16 + kq * 4 + reg;
      float* po = out + m * 512 + eb + wn * 64 + rlane;
#pragma unroll
      for (int j = 0; j < 4; ++j) po[j * 16] = acc[i][j][reg] + bj[j];
    }
  }
}

// ---------------------------------------------------------------------------
// Fallback fp32 fused GEMM (round-1 path) if workspace is too small.
// ---------------------------------------------------------------------------
__global__ __launch_bounds__(256) void w2eff_f32_kernel(
    const float* __restrict__ Wm, const float* __restrict__ Wmsg,
    float* __restrict__ W2) {
  __shared__ float As[32][33];
  __shared__ float Bs[32][33];
  const int t = threadIdx.x;
  const int eb = blockIdx.y * 32;
  const int db = blockIdx.x * 32;
  const int tx = t % 16, ty = t / 16;
  const int lr = t / 8;
  const int lc = (t % 8) * 4;
  float a00 = 0.f, a01 = 0.f, a10 = 0.f, a11 = 0.f;
  for (int c0 = 0; c0 < 512; c0 += 32) {
    float4 av = *(const float4*)&Wm[(size_t)(eb + lr) * 1024 + 512 + c0 + lc];
    float4 bv = *(const float4*)&Wmsg[(size_t)(c0 + lr) * 512 + db + lc];
    As[lr][lc + 0] = av.x; As[lr][lc + 1] = av.y;
    As[lr][lc + 2] = av.z; As[lr][lc + 3] = av.w;
    Bs[lr][lc + 0] = bv.x; Bs[lr][lc + 1] = bv.y;
    Bs[lr][lc + 2] = bv.z; Bs[lr][lc + 3] = bv.w;
    __syncthreads();
#pragma unroll
    for (int kk = 0; kk < 32; kk++) {
      float x0 = As[2 * ty + 0][kk], x1 = As[2 * ty + 1][kk];
      float y0 = Bs[kk][2 * tx + 0], y1 = Bs[kk][2 * tx + 1];
      a00 += x0 * y0; a01 += x0 * y1;
      a10 += x1 * y0; a11 += x1 * y1;
    }
    __syncthreads();
  }
  W2[(size_t)(eb + 2 * ty + 0) * 512 + db + 2 * tx + 0] = a00;
  W2[(size_t)(eb + 2 * ty + 0) * 512 + db + 2 * tx + 1] = a01;
  W2[(size_t)(eb + 2 * ty + 1) * 512 + db + 2 * tx + 0] = a10;
  W2[(size_t)(eb + 2 * ty + 1) * 512 + db + 2 * tx + 1] = a11;
}

__global__ __launch_bounds__(256) void fused_gemm_f32_kernel(
    const float* __restrict__ h, const int* __restrict__ sel,
    const float* __restrict__ Wm, const float* __restrict__ W2,
    const float* __restrict__ bias_eff, float* __restrict__ out) {
  const int r = blockIdx.y;
  const int eb = blockIdx.x * 256;
  const int t = threadIdx.x;
  __shared__ float As[64][33];
  __shared__ float Ws[256][33];
  __shared__ int sel_s[K_];
  if (t < K_) sel_s[t] = sel[r * K_ + t];
  __syncthreads();
  const size_t hr = (size_t)r * RBD;
  const size_t s0 = (size_t)sel_s[0] * RBD;
  const size_t s1 = (size_t)sel_s[1] * RBD;
  const size_t s2 = (size_t)sel_s[2] * RBD;
  const size_t s3 = (size_t)sel_s[3] * RBD;
  const int tb = t % 8;
  const int te = t / 8;
  const int ab = t / 4;
  const int ac = (t % 4) * 8;
  float acc[8][8] = {};
  for (int d0 = 0; d0 < 1024; d0 += 32) {
    if (d0 < 512) {
      const float* src = h + hr + (size_t)ab * 512 + d0 + ac;
      float4 v0 = *(const float4*)(src);
      float4 v1 = *(const float4*)(src + 4);
      As[ab][ac + 0] = v0.x; As[ab][ac + 1] = v0.y;
      As[ab][ac + 2] = v0.z; As[ab][ac + 3] = v0.w;
      As[ab][ac + 4] = v1.x; As[ab][ac + 5] = v1.y;
      As[ab][ac + 6] = v1.z; As[ab][ac + 7] = v1.w;
    } else {
      const size_t off = (size_t)ab * 512 + (d0 - 512) + ac;
      const float* p0 = h + s0 + off;
      const float* p1 = h + s1 + off;
      const float* p2 = h + s2 + off;
      const float* p3 = h + s3 + off;
      float4 q0 = *(const float4*)p0, q0b = *(const float4*)(p0 + 4);
      float4 q1 = *(const float4*)p1, q1b = *(const float4*)(p1 + 4);
      float4 q2 = *(const float4*)p2, q2b = *(const float4*)(p2 + 4);
      float4 q3 = *(const float4*)p3, q3b = *(const float4*)(p3 + 4);
      As[ab][ac + 0] = 0.25f * (q0.x + q1.x + q2.x + q3.x);
      As[ab][ac + 1] = 0.25f * (q0.y + q1.y + q2.y + q3.y);
      As[ab][ac + 2] = 0.25f * (q0.z + q1.z + q2.z + q3.z);
      As[ab][ac + 3] = 0.25f * (q0.w + q1.w + q2.w + q3.w);
      As[ab][ac + 4] = 0.25f * (q0b.x + q1b.x + q2b.x + q3b.x);
      As[ab][ac + 5] = 0.25f * (q0b.y + q1b.y + q2b.y + q3b.y);
      As[ab][ac + 6] = 0.25f * (q0b.z + q1b.z + q2b.z + q3b.z);
      As[ab][ac + 7] = 0.25f * (q0b.w + q1b.w + q2b.w + q3b.w);
    }
    {
      const float* src = (d0 < 512)
          ? (Wm + (size_t)(eb + t) * 1024 + d0)
          : (W2 + (size_t)(eb + t) * 512 + (d0 - 512));
#pragma unroll
      for (int j = 0; j < 8; j++) {
        float4 v = *(const float4*)(src + 4 * j);
        Ws[t][4 * j + 0] = v.x; Ws[t][4 * j + 1] = v.y;
        Ws[t][4 * j + 2] = v.z; Ws[t][4 * j + 3] = v.w;
      }
    }
    __syncthreads();
#pragma unroll
    for (int kk = 0; kk < 32; kk++) {
      float a[8], wv[8];
#pragma unroll
      for (int i = 0; i < 8; i++) a[i] = As[tb + 8 * i][kk];
#pragma unroll
      for (int j = 0; j < 8; j++) wv[j] = Ws[te + 32 * j][kk];
#pragma unroll
      for (int i = 0; i < 8; i++)
#pragma unroll
        for (int j = 0; j < 8; j++) acc[i][j] += a[i] * wv[j];
    }
    __syncthreads();
  }
  float be[8];
#pragma unroll
  for (int j = 0; j < 8; j++) be[j] = bias_eff[eb + te + 32 * j];
#pragma unroll
  for (int i = 0; i < 8; i++) {
    const int b = tb + 8 * i;
#pragma unroll
    for (int j = 0; j < 8; j++) {
      const int e = eb + te + 32 * j;
      out[hr + (size_t)b * 512 + e] = acc[i][j] + be[j];
    }
  }
}

// ---------------------------------------------------------------------------
extern "C" void kernel_launch(void* const* d_in, const int* in_sizes, int n_in,
                              void* d_out, int out_size, void* d_ws,
                              size_t ws_size, hipStream_t stream) {
  const float* h       = (const float*)d_in[0];
  const int*   nbrs    = (const int*)d_in[1];
  const float* W_msg   = (const float*)d_in[2];
  const float* b_msg   = (const float*)d_in[3];
  const float* W_merge = (const float*)d_in[4];
  const float* b_merge = (const float*)d_in[5];
  float* out = (float*)d_out;
  char* ws = (char*)d_ws;

  const size_t NEED = 8192 + (size_t)512 * 1024 * 2 + (size_t)M_TOT * 1024 * 2;

  if (ws_size >= NEED) {
    int*            sel      = (int*)ws;                       // 4 KB
    float*          bias_eff = (float*)(ws + 4096);            // 2 KB
    unsigned short* Wbig     = (unsigned short*)(ws + 8192);   // 1 MB
    unsigned short* Abig     = (unsigned short*)(ws + 8192 + 512 * 1024 * 2);

    sims_topk_kernel<<<R_, 256, 0, stream>>>(h, nbrs, sel, out + OUT_ELEMS);
    bias_kernel<<<2, 256, 0, stream>>>(W_merge, b_msg, b_merge, bias_eff);
    w2eff_kernel<<<dim3(16, 16), 256, 0, stream>>>(W_merge, W_msg, Wbig);
    wconv_kernel<<<256, 256, 0, stream>>>(W_merge, Wbig);
    abig_kernel<<<R_, 256, 0, stream>>>(h, sel, Abig);
    mfma_gemm_kernel<<<dim3(4, 128), 256, 0, stream>>>(Abig, Wbig, bias_eff,
                                                       out);
  } else {
    int*   sel      = (int*)ws;
    float* W2       = (float*)(ws + 4096);
    float* bias_eff = (float*)(ws + 4096 + 512 * 512 * 4);
    sims_topk_kernel<<<R_, 256, 0, stream>>>(h, nbrs, sel, out + OUT_ELEMS);
    bias_kernel<<<2, 256, 0, stream>>>(W_merge, b_msg, b_merge, bias_eff);
    w2eff_f32_kernel<<<dim3(16, 16), 256, 0, stream>>>(W_merge, W_msg, W2);
    fused_gemm_f32_kernel<<<dim3(2, R_), 256, 0, stream>>>(h, sel, W_merge, W2,
                                                           bias_eff, out);
  }
}

// Round 3
// 130.038 us; speedup vs baseline: 3.3095x; 1.1153x over previous
//
#include <hip/hip_runtime.h>
#include <hip/hip_bf16.h>

#define R_ 256
#define B_ 64
#define D_ 512
#define N_ 16
#define K_ 4
#define RBD (B_ * D_)          // 32768 floats per region
#define OUT_ELEMS (R_ * B_ * D_)
#define M_TOT (R_ * B_)        // 16384
#define K_TOT 1024
#define SLICES 8               // sims reduction slices (RBD/8 = 4096 floats)

typedef __attribute__((address_space(1))) unsigned int g_u32;
typedef __attribute__((address_space(3))) unsigned int l_u32;
using f32x4 = __attribute__((ext_vector_type(4))) float;
using bf16x8 = __attribute__((ext_vector_type(8))) short;

__device__ inline unsigned short f2bf(float x) {
  __hip_bfloat16 b = __float2bfloat16(x);
  return *reinterpret_cast<unsigned short*>(&b);
}

// ---------------------------------------------------------------------------
// Kernel 1a: partial sims. Grid (R, SLICES), 256 thr. Wave w owns neighbors
// 4w..4w+3 over a 4096-float slice. Deterministic (no atomics): partials go
// to sims_p[r][n][s], reduced in fixed order by topk_kernel.
// ---------------------------------------------------------------------------
__global__ __launch_bounds__(256) void sims_part_kernel(
    const float* __restrict__ h, const int* __restrict__ nbrs,
    float* __restrict__ sims_p) {
  const int r = blockIdx.x;
  const int s = blockIdx.y;
  const int t = threadIdx.x;
  const int lane = t & 63;
  const int wave = t >> 6;
  __shared__ int nb_s[N_];
  if (t < N_) nb_s[t] = nbrs[r * N_ + t];
  __syncthreads();
  const int n0 = wave * 4;
  const size_t base = (size_t)s * (RBD / SLICES);
  const float4* hr  = (const float4*)(h + (size_t)r * RBD + base);
  const float4* hn0 = (const float4*)(h + (size_t)nb_s[n0 + 0] * RBD + base);
  const float4* hn1 = (const float4*)(h + (size_t)nb_s[n0 + 1] * RBD + base);
  const float4* hn2 = (const float4*)(h + (size_t)nb_s[n0 + 2] * RBD + base);
  const float4* hn3 = (const float4*)(h + (size_t)nb_s[n0 + 3] * RBD + base);
  float a0 = 0.f, a1 = 0.f, a2 = 0.f, a3 = 0.f;
#pragma unroll 4
  for (int i = lane; i < RBD / SLICES / 4; i += 64) {
    float4 x = hr[i];
    float4 y0 = hn0[i], y1 = hn1[i], y2 = hn2[i], y3 = hn3[i];
    a0 += x.x * y0.x + x.y * y0.y + x.z * y0.z + x.w * y0.w;
    a1 += x.x * y1.x + x.y * y1.y + x.z * y1.z + x.w * y1.w;
    a2 += x.x * y2.x + x.y * y2.y + x.z * y2.z + x.w * y2.w;
    a3 += x.x * y3.x + x.y * y3.y + x.z * y3.z + x.w * y3.w;
  }
  float v[4] = {a0, a1, a2, a3};
#pragma unroll
  for (int n = 0; n < 4; n++) {
    float x = v[n];
#pragma unroll
    for (int off = 32; off > 0; off >>= 1) x += __shfl_down(x, off);
    if (lane == 0) sims_p[((size_t)r * N_ + n0 + n) * SLICES + s] = x;
  }
}

// ---------------------------------------------------------------------------
// Kernel 1b: reduce partials (fixed order) + stable top-4 (strict >, first
// index wins = jax.lax.top_k tie rule).
// ---------------------------------------------------------------------------
__global__ __launch_bounds__(64) void topk_kernel(
    const float* __restrict__ sims_p, const int* __restrict__ nbrs,
    int* __restrict__ sel, float* __restrict__ fanin) {
  const int r = blockIdx.x;
  const int t = threadIdx.x;
  __shared__ float sims_s[N_];
  __shared__ int nb_s[N_];
  if (t < N_) {
    const float* p = sims_p + ((size_t)r * N_ + t) * SLICES;
    float acc = 0.f;
#pragma unroll
    for (int s = 0; s < SLICES; s++) acc += p[s];
    sims_s[t] = acc;
    nb_s[t] = nbrs[r * N_ + t];
  }
  __syncthreads();
  if (t == 0) {
    unsigned used = 0;
#pragma unroll
    for (int k = 0; k < K_; k++) {
      float best = -3.0e38f;
      int bi = 0;
      for (int n = 0; n < N_; n++) {
        if (used & (1u << n)) continue;
        float vv = sims_s[n];
        if (vv > best) { best = vv; bi = n; }
      }
      used |= 1u << bi;
      sel[r * K_ + k] = nb_s[bi];
    }
    if (r == 0) *fanin = 4.0f;
  }
}

// ---------------------------------------------------------------------------
// Kernel 2: W2eff[e][d] = sum_c Wm[e][512+c] * Wmsg[c][d] -> bf16 Wbig[e][512+d]
// ---------------------------------------------------------------------------
__global__ __launch_bounds__(256) void w2eff_kernel(
    const float* __restrict__ Wm, const float* __restrict__ Wmsg,
    unsigned short* __restrict__ Wbig) {
  __shared__ float As[32][33];
  __shared__ float Bs[32][33];
  const int t = threadIdx.x;
  const int eb = blockIdx.y * 32;
  const int db = blockIdx.x * 32;
  const int tx = t % 16, ty = t / 16;
  const int lr = t / 8;
  const int lc = (t % 8) * 4;
  float a00 = 0.f, a01 = 0.f, a10 = 0.f, a11 = 0.f;
  for (int c0 = 0; c0 < 512; c0 += 32) {
    float4 av = *(const float4*)&Wm[(size_t)(eb + lr) * 1024 + 512 + c0 + lc];
    float4 bv = *(const float4*)&Wmsg[(size_t)(c0 + lr) * 512 + db + lc];
    As[lr][lc + 0] = av.x; As[lr][lc + 1] = av.y;
    As[lr][lc + 2] = av.z; As[lr][lc + 3] = av.w;
    Bs[lr][lc + 0] = bv.x; Bs[lr][lc + 1] = bv.y;
    Bs[lr][lc + 2] = bv.z; Bs[lr][lc + 3] = bv.w;
    __syncthreads();
#pragma unroll
    for (int kk = 0; kk < 32; kk++) {
      float x0 = As[2 * ty + 0][kk], x1 = As[2 * ty + 1][kk];
      float y0 = Bs[kk][2 * tx + 0], y1 = Bs[kk][2 * tx + 1];
      a00 += x0 * y0; a01 += x0 * y1;
      a10 += x1 * y0; a11 += x1 * y1;
    }
    __syncthreads();
  }
  Wbig[(size_t)(eb + 2 * ty + 0) * 1024 + 512 + db + 2 * tx + 0] = f2bf(a00);
  Wbig[(size_t)(eb + 2 * ty + 0) * 1024 + 512 + db + 2 * tx + 1] = f2bf(a01);
  Wbig[(size_t)(eb + 2 * ty + 1) * 1024 + 512 + db + 2 * tx + 0] = f2bf(a10);
  Wbig[(size_t)(eb + 2 * ty + 1) * 1024 + 512 + db + 2 * tx + 1] = f2bf(a11);
}

// ---------------------------------------------------------------------------
// Kernel 3: bias_eff[e] = b_merge[e] + sum_c b_msg[c] * Wm[e][512+c]  (fp32)
// ---------------------------------------------------------------------------
__global__ __launch_bounds__(256) void bias_kernel(
    const float* __restrict__ Wm, const float* __restrict__ b_msg,
    const float* __restrict__ b_merge, float* __restrict__ bias_eff) {
  const int e = blockIdx.x * 256 + threadIdx.x;
  const float4* bp = (const float4*)b_msg;
  const float4* wp = (const float4*)&Wm[(size_t)e * 1024 + 512];
  float acc = 0.f;
  for (int c = 0; c < 128; c++) {
    float4 b4 = bp[c], w4 = wp[c];
    acc += b4.x * w4.x + b4.y * w4.y + b4.z * w4.z + b4.w * w4.w;
  }
  bias_eff[e] = acc + b_merge[e];
}

// ---------------------------------------------------------------------------
// Kernel 4: Wbig first half: Wbig[e][d] = bf16(Wm[e][d]) for d<512
// ---------------------------------------------------------------------------
__global__ __launch_bounds__(256) void wconv_kernel(
    const float* __restrict__ Wm, unsigned short* __restrict__ Wbig) {
  const int i = blockIdx.x * 256 + threadIdx.x;
  const int e = i >> 7;
  const int c4 = (i & 127) * 4;
  float4 v = *(const float4*)&Wm[(size_t)e * 1024 + c4];
  ushort4 o;
  o.x = f2bf(v.x); o.y = f2bf(v.y); o.z = f2bf(v.z); o.w = f2bf(v.w);
  *(ushort4*)&Wbig[(size_t)e * 1024 + c4] = o;
}

// ---------------------------------------------------------------------------
// Kernel 5: Abig[r*64+b][0..511] = bf16(h[r][b][:]);
//           Abig[r*64+b][512..1023] = bf16(mean_k h[sel[r][k]][b][:])
// Grid (R, 4): each block does 16 of the 64 b-rows -> 4 blocks/CU.
// ---------------------------------------------------------------------------
__global__ __launch_bounds__(256) void abig_kernel(
    const float* __restrict__ h, const int* __restrict__ sel,
    unsigned short* __restrict__ Abig) {
  const int r = blockIdx.x;
  const int rs = blockIdx.y * 16;  // row slice base
  const int t = threadIdx.x;
  __shared__ int sel_s[K_];
  if (t < K_) sel_s[t] = sel[r * K_ + t];
  __syncthreads();
  const size_t hr = (size_t)r * RBD;
  const size_t s0 = (size_t)sel_s[0] * RBD;
  const size_t s1 = (size_t)sel_s[1] * RBD;
  const size_t s2 = (size_t)sel_s[2] * RBD;
  const size_t s3 = (size_t)sel_s[3] * RBD;
  // 16 rows x 512 cols, float4 granularity: 2048 chunks
  for (int i = t; i < 2048; i += 256) {
    const int row = rs + (i >> 7);
    const int c = (i & 127) * 4;
    const size_t off = (size_t)row * 512 + c;
    float4 v = *(const float4*)&h[hr + off];
    ushort4 o;
    o.x = f2bf(v.x); o.y = f2bf(v.y); o.z = f2bf(v.z); o.w = f2bf(v.w);
    *(ushort4*)&Abig[((size_t)r * 64 + row) * 1024 + c] = o;
    float4 q0 = *(const float4*)&h[s0 + off];
    float4 q1 = *(const float4*)&h[s1 + off];
    float4 q2 = *(const float4*)&h[s2 + off];
    float4 q3 = *(const float4*)&h[s3 + off];
    ushort4 m;
    m.x = f2bf(0.25f * (q0.x + q1.x + q2.x + q3.x));
    m.y = f2bf(0.25f * (q0.y + q1.y + q2.y + q3.y));
    m.z = f2bf(0.25f * (q0.z + q1.z + q2.z + q3.z));
    m.w = f2bf(0.25f * (q0.w + q1.w + q2.w + q3.w));
    *(ushort4*)&Abig[((size_t)r * 64 + row) * 1024 + 512 + c] = m;
  }
}

// ---------------------------------------------------------------------------
// Kernel 6: bf16 MFMA GEMM. out[m][e] = bias[e] + sum_k Abig[m][k]*Wbig[e][k]
// M=16384, N=512, K=1024. Tile 128x128, BK=64. XOR-swizzled LDS via
// pre-swizzled global source (linear gload_lds dest + swizzled read).
// ---------------------------------------------------------------------------
__global__ __launch_bounds__(256) void mfma_gemm_kernel(
    const unsigned short* __restrict__ A, const unsigned short* __restrict__ W,
    const float* __restrict__ bias, float* __restrict__ out) {
  const int t = threadIdx.x;
  const int lane = t & 63;
  const int w = t >> 6;
  const int m0 = blockIdx.y * 128;
  const int eb = blockIdx.x * 128;
  __shared__ unsigned short As[128 * 64];
  __shared__ unsigned short Ws[128 * 64];
  const int wm = w >> 1, wn = w & 1;
  const int rlane = lane & 15;
  const int kq = lane >> 4;

  f32x4 acc[4][4] = {};

  const char* Ab = (const char*)A;
  const char* Wb = (const char*)W;
  char* smemA = (char*)As;
  char* smemW = (char*)Ws;
  const int row_in_sweep = t >> 3;
  const int slot_st = t & 7;

  for (int kt = 0; kt < 16; ++kt) {
#pragma unroll
    for (int q = 0; q < 4; ++q) {
      const int row = q * 32 + row_in_sweep;
      const int slot = slot_st ^ (row & 7);
      const char* ga = Ab + ((size_t)(m0 + row) * 2048 + kt * 128 + slot * 16);
      const char* gw = Wb + ((size_t)(eb + row) * 2048 + kt * 128 + slot * 16);
      char* la = smemA + q * 4096 + w * 1024;
      char* lw = smemW + q * 4096 + w * 1024;
      __builtin_amdgcn_global_load_lds((const g_u32*)ga, (l_u32*)la, 16, 0, 0);
      __builtin_amdgcn_global_load_lds((const g_u32*)gw, (l_u32*)lw, 16, 0, 0);
    }
    __syncthreads();
#pragma unroll
    for (int ks = 0; ks < 2; ++ks) {
      bf16x8 a[4], b[4];
#pragma unroll
      for (int i = 0; i < 4; ++i) {
        const int row = wm * 64 + i * 16 + rlane;
        const int slot = (ks * 4 + kq) ^ (row & 7);
        a[i] = *(const bf16x8*)(smemA + row * 128 + slot * 16);
      }
#pragma unroll
      for (int j = 0; j < 4; ++j) {
        const int row = wn * 64 + j * 16 + rlane;
        const int slot = (ks * 4 + kq) ^ (row & 7);
        b[j] = *(const bf16x8*)(smemW + row * 128 + slot * 16);
      }
#pragma unroll
      for (int i = 0; i < 4; ++i)
#pragma unroll
        for (int j = 0; j < 4; ++j)
          acc[i][j] = __builtin_amdgcn_mfma_f32_16x16x32_bf16(
              a[i], b[j], acc[i][j], 0, 0, 0);
    }
    __syncthreads();
  }

  float bj[4];
#pragma unroll
  for (int j = 0; j < 4; ++j) bj[j] = bias[eb + wn * 64 + j * 16 + rlane];
#pragma unroll
  for (int i = 0; i < 4; ++i) {
#pragma unroll
    for (int reg = 0; reg < 4; ++reg) {
      const size_t m = (size_t)m0 + wm * 64 + i * 16 + kq * 4 + reg;
      float* po = out + m * 512 + eb + wn * 64 + rlane;
#pragma unroll
      for (int j = 0; j < 4; ++j) po[j * 16] = acc[i][j][reg] + bj[j];
    }
  }
}

// ---------------------------------------------------------------------------
// Fallback fp32 path (small workspace): round-1 kernels.
// ---------------------------------------------------------------------------
__global__ __launch_bounds__(256) void sims_topk_kernel(
    const float* __restrict__ h, const int* __restrict__ nbrs,
    int* __restrict__ sel, float* __restrict__ fanin) {
  const int r = blockIdx.x;
  const int t = threadIdx.x;
  const int lane = t & 63;
  const int wave = t >> 6;
  __shared__ float sims_s[N_];
  __shared__ int nb_s[N_];
  if (t < N_) nb_s[t] = nbrs[r * N_ + t];
  __syncthreads();
  const int n0 = wave * 4;
  const float4* hr  = (const float4*)(h + (size_t)r * RBD);
  const float4* hn0 = (const float4*)(h + (size_t)nb_s[n0 + 0] * RBD);
  const float4* hn1 = (const float4*)(h + (size_t)nb_s[n0 + 1] * RBD);
  const float4* hn2 = (const float4*)(h + (size_t)nb_s[n0 + 2] * RBD);
  const float4* hn3 = (const float4*)(h + (size_t)nb_s[n0 + 3] * RBD);
  float a0 = 0.f, a1 = 0.f, a2 = 0.f, a3 = 0.f;
  for (int i = lane; i < RBD / 4; i += 64) {
    float4 x = hr[i];
    float4 y0 = hn0[i], y1 = hn1[i], y2 = hn2[i], y3 = hn3[i];
    a0 += x.x * y0.x + x.y * y0.y + x.z * y0.z + x.w * y0.w;
    a1 += x.x * y1.x + x.y * y1.y + x.z * y1.z + x.w * y1.w;
    a2 += x.x * y2.x + x.y * y2.y + x.z * y2.z + x.w * y2.w;
    a3 += x.x * y3.x + x.y * y3.y + x.z * y3.z + x.w * y3.w;
  }
  float v[4] = {a0, a1, a2, a3};
#pragma unroll
  for (int n = 0; n < 4; n++) {
    float x = v[n];
#pragma unroll
    for (int off = 32; off > 0; off >>= 1) x += __shfl_down(x, off);
    if (lane == 0) sims_s[n0 + n] = x;
  }
  __syncthreads();
  if (t == 0) {
    unsigned used = 0;
#pragma unroll
    for (int k = 0; k < K_; k++) {
      float best = -3.0e38f;
      int bi = 0;
      for (int n = 0; n < N_; n++) {
        if (used & (1u << n)) continue;
        float vv = sims_s[n];
        if (vv > best) { best = vv; bi = n; }
      }
      used |= 1u << bi;
      sel[r * K_ + k] = nb_s[bi];
    }
    if (r == 0) *fanin = 4.0f;
  }
}

__global__ __launch_bounds__(256) void w2eff_f32_kernel(
    const float* __restrict__ Wm, const float* __restrict__ Wmsg,
    float* __restrict__ W2) {
  __shared__ float As[32][33];
  __shared__ float Bs[32][33];
  const int t = threadIdx.x;
  const int eb = blockIdx.y * 32;
  const int db = blockIdx.x * 32;
  const int tx = t % 16, ty = t / 16;
  const int lr = t / 8;
  const int lc = (t % 8) * 4;
  float a00 = 0.f, a01 = 0.f, a10 = 0.f, a11 = 0.f;
  for (int c0 = 0; c0 < 512; c0 += 32) {
    float4 av = *(const float4*)&Wm[(size_t)(eb + lr) * 1024 + 512 + c0 + lc];
    float4 bv = *(const float4*)&Wmsg[(size_t)(c0 + lr) * 512 + db + lc];
    As[lr][lc + 0] = av.x; As[lr][lc + 1] = av.y;
    As[lr][lc + 2] = av.z; As[lr][lc + 3] = av.w;
    Bs[lr][lc + 0] = bv.x; Bs[lr][lc + 1] = bv.y;
    Bs[lr][lc + 2] = bv.z; Bs[lr][lc + 3] = bv.w;
    __syncthreads();
#pragma unroll
    for (int kk = 0; kk < 32; kk++) {
      float x0 = As[2 * ty + 0][kk], x1 = As[2 * ty + 1][kk];
      float y0 = Bs[kk][2 * tx + 0], y1 = Bs[kk][2 * tx + 1];
      a00 += x0 * y0; a01 += x0 * y1;
      a10 += x1 * y0; a11 += x1 * y1;
    }
    __syncthreads();
  }
  W2[(size_t)(eb + 2 * ty + 0) * 512 + db + 2 * tx + 0] = a00;
  W2[(size_t)(eb + 2 * ty + 0) * 512 + db + 2 * tx + 1] = a01;
  W2[(size_t)(eb + 2 * ty + 1) * 512 + db + 2 * tx + 0] = a10;
  W2[(size_t)(eb + 2 * ty + 1) * 512 + db + 2 * tx + 1] = a11;
}

__global__ __launch_bounds__(256) void fused_gemm_f32_kernel(
    const float* __restrict__ h, const int* __restrict__ sel,
    const float* __restrict__ Wm, const float* __restrict__ W2,
    const float* __restrict__ bias_eff, float* __restrict__ out) {
  const int r = blockIdx.y;
  const int eb = blockIdx.x * 256;
  const int t = threadIdx.x;
  __shared__ float As[64][33];
  __shared__ float Ws[256][33];
  __shared__ int sel_s[K_];
  if (t < K_) sel_s[t] = sel[r * K_ + t];
  __syncthreads();
  const size_t hr = (size_t)r * RBD;
  const size_t s0 = (size_t)sel_s[0] * RBD;
  const size_t s1 = (size_t)sel_s[1] * RBD;
  const size_t s2 = (size_t)sel_s[2] * RBD;
  const size_t s3 = (size_t)sel_s[3] * RBD;
  const int tb = t % 8;
  const int te = t / 8;
  const int ab = t / 4;
  const int ac = (t % 4) * 8;
  float acc[8][8] = {};
  for (int d0 = 0; d0 < 1024; d0 += 32) {
    if (d0 < 512) {
      const float* src = h + hr + (size_t)ab * 512 + d0 + ac;
      float4 v0 = *(const float4*)(src);
      float4 v1 = *(const float4*)(src + 4);
      As[ab][ac + 0] = v0.x; As[ab][ac + 1] = v0.y;
      As[ab][ac + 2] = v0.z; As[ab][ac + 3] = v0.w;
      As[ab][ac + 4] = v1.x; As[ab][ac + 5] = v1.y;
      As[ab][ac + 6] = v1.z; As[ab][ac + 7] = v1.w;
    } else {
      const size_t off = (size_t)ab * 512 + (d0 - 512) + ac;
      const float* p0 = h + s0 + off;
      const float* p1 = h + s1 + off;
      const float* p2 = h + s2 + off;
      const float* p3 = h + s3 + off;
      float4 q0 = *(const float4*)p0, q0b = *(const float4*)(p0 + 4);
      float4 q1 = *(const float4*)p1, q1b = *(const float4*)(p1 + 4);
      float4 q2 = *(const float4*)p2, q2b = *(const float4*)(p2 + 4);
      float4 q3 = *(const float4*)p3, q3b = *(const float4*)(p3 + 4);
      As[ab][ac + 0] = 0.25f * (q0.x + q1.x + q2.x + q3.x);
      As[ab][ac + 1] = 0.25f * (q0.y + q1.y + q2.y + q3.y);
      As[ab][ac + 2] = 0.25f * (q0.z + q1.z + q2.z + q3.z);
      As[ab][ac + 3] = 0.25f * (q0.w + q1.w + q2.w + q3.w);
      As[ab][ac + 4] = 0.25f * (q0b.x + q1b.x + q2b.x + q3b.x);
      As[ab][ac + 5] = 0.25f * (q0b.y + q1b.y + q2b.y + q3b.y);
      As[ab][ac + 6] = 0.25f * (q0b.z + q1b.z + q2b.z + q3b.z);
      As[ab][ac + 7] = 0.25f * (q0b.w + q1b.w + q2b.w + q3b.w);
    }
    {
      const float* src = (d0 < 512)
          ? (Wm + (size_t)(eb + t) * 1024 + d0)
          : (W2 + (size_t)(eb + t) * 512 + (d0 - 512));
#pragma unroll
      for (int j = 0; j < 8; j++) {
        float4 v = *(const float4*)(src + 4 * j);
        Ws[t][4 * j + 0] = v.x; Ws[t][4 * j + 1] = v.y;
        Ws[t][4 * j + 2] = v.z; Ws[t][4 * j + 3] = v.w;
      }
    }
    __syncthreads();
#pragma unroll
    for (int kk = 0; kk < 32; kk++) {
      float a[8], wv[8];
#pragma unroll
      for (int i = 0; i < 8; i++) a[i] = As[tb + 8 * i][kk];
#pragma unroll
      for (int j = 0; j < 8; j++) wv[j] = Ws[te + 32 * j][kk];
#pragma unroll
      for (int i = 0; i < 8; i++)
#pragma unroll
        for (int j = 0; j < 8; j++) acc[i][j] += a[i] * wv[j];
    }
    __syncthreads();
  }
  float be[8];
#pragma unroll
  for (int j = 0; j < 8; j++) be[j] = bias_eff[eb + te + 32 * j];
#pragma unroll
  for (int i = 0; i < 8; i++) {
    const int b = tb + 8 * i;
#pragma unroll
    for (int j = 0; j < 8; j++) {
      const int e = eb + te + 32 * j;
      out[hr + (size_t)b * 512 + e] = acc[i][j] + be[j];
    }
  }
}

// ---------------------------------------------------------------------------
extern "C" void kernel_launch(void* const* d_in, const int* in_sizes, int n_in,
                              void* d_out, int out_size, void* d_ws,
                              size_t ws_size, hipStream_t stream) {
  const float* h       = (const float*)d_in[0];
  const int*   nbrs    = (const int*)d_in[1];
  const float* W_msg   = (const float*)d_in[2];
  const float* b_msg   = (const float*)d_in[3];
  const float* W_merge = (const float*)d_in[4];
  const float* b_merge = (const float*)d_in[5];
  float* out = (float*)d_out;
  char* ws = (char*)d_ws;

  const size_t SIMS_P_BYTES = (size_t)R_ * N_ * SLICES * 4;  // 128 KB
  const size_t NEED = 8192 + SIMS_P_BYTES + (size_t)512 * 1024 * 2 +
                      (size_t)M_TOT * 1024 * 2;

  if (ws_size >= NEED) {
    int*            sel      = (int*)ws;                          // 4 KB
    float*          bias_eff = (float*)(ws + 4096);               // 2 KB
    float*          sims_p   = (float*)(ws + 8192);               // 128 KB
    unsigned short* Wbig     = (unsigned short*)(ws + 8192 + SIMS_P_BYTES);
    unsigned short* Abig =
        (unsigned short*)(ws + 8192 + SIMS_P_BYTES + 512 * 1024 * 2);

    sims_part_kernel<<<dim3(R_, SLICES), 256, 0, stream>>>(h, nbrs, sims_p);
    topk_kernel<<<R_, 64, 0, stream>>>(sims_p, nbrs, sel, out + OUT_ELEMS);
    bias_kernel<<<2, 256, 0, stream>>>(W_merge, b_msg, b_merge, bias_eff);
    w2eff_kernel<<<dim3(16, 16), 256, 0, stream>>>(W_merge, W_msg, Wbig);
    wconv_kernel<<<256, 256, 0, stream>>>(W_merge, Wbig);
    abig_kernel<<<dim3(R_, 4), 256, 0, stream>>>(h, sel, Abig);
    mfma_gemm_kernel<<<dim3(4, 128), 256, 0, stream>>>(Abig, Wbig, bias_eff,
                                                       out);
  } else {
    int*   sel      = (int*)ws;
    float* W2       = (float*)(ws + 4096);
    float* bias_eff = (float*)(ws + 4096 + 512 * 512 * 4);
    sims_topk_kernel<<<R_, 256, 0, stream>>>(h, nbrs, sel, out + OUT_ELEMS);
    bias_kernel<<<2, 256, 0, stream>>>(W_merge, b_msg, b_merge, bias_eff);
    w2eff_f32_kernel<<<dim3(16, 16), 256, 0, stream>>>(W_merge, W_msg, W2);
    fused_gemm_f32_kernel<<<dim3(2, R_), 256, 0, stream>>>(h, sel, W_merge, W2,
                                                           bias_eff, out);
  }
}